// Round 1
// baseline (344.786 us; speedup 1.0000x reference)
//
#include <hip/hip_runtime.h>

// out[b, t, h] = sum_{j=0..4} x[b, t+j, h] * attn[b, t+j]
// B=32, H=768, LENGTH=2048, PADDED=2052, fp32 in/out. Memory-bound.

#define LEN     2048
#define WIDTH   5
#define PADDED  (LEN + WIDTH - 1)   // 2052
#define BATCH   32
#define HDIM    768
#define H4      (HDIM / 4)          // 192 float4 per row
#define TCHUNK  32
#define NCHUNK  (LEN / TCHUNK)      // 64

__global__ __launch_bounds__(256) void widthap_kernel(
    const float4* __restrict__ x,
    const float*  __restrict__ attn,
    float4*       __restrict__ out)
{
    const int tid   = blockIdx.x * blockDim.x + threadIdx.x;
    const int h4    = tid % H4;            // lane-contiguous -> coalesced
    const int rest  = tid / H4;
    const int b     = rest % BATCH;
    const int chunk = rest / BATCH;
    if (chunk >= NCHUNK) return;           // grid is exact; defensive only
    const int t0 = chunk * TCHUNK;

    const float4* xp = x   + ((size_t)b * PADDED + t0) * H4 + h4;
    const float*  ap = attn +  (size_t)b * PADDED + t0;
    float4*       op = out + ((size_t)b * LEN    + t0) * H4 + h4;

    // ring of pre-weighted values w[j] = x[t0+j]*attn[t0+j]; each x read once
    float4 w0, w1, w2, w3, w4;

    auto loadw = [&](int j) -> float4 {
        const float  a = ap[j];                    // wave-uniform broadcast
        const float4 v = xp[(size_t)j * H4];       // coalesced 16B/lane
        return make_float4(v.x * a, v.y * a, v.z * a, v.w * a);
    };

    w0 = loadw(0);
    w1 = loadw(1);
    w2 = loadw(2);
    w3 = loadw(3);

    #pragma unroll 8
    for (int i = 0; i < TCHUNK; ++i) {
        w4 = loadw(i + 4);
        float4 s;
        s.x = w0.x + w1.x + w2.x + w3.x + w4.x;
        s.y = w0.y + w1.y + w2.y + w3.y + w4.y;
        s.z = w0.z + w1.z + w2.z + w3.z + w4.z;
        s.w = w0.w + w1.w + w2.w + w3.w + w4.w;
        op[(size_t)i * H4] = s;
        w0 = w1; w1 = w2; w2 = w3; w3 = w4;
    }
}

extern "C" void kernel_launch(void* const* d_in, const int* in_sizes, int n_in,
                              void* d_out, int out_size, void* d_ws, size_t ws_size,
                              hipStream_t stream) {
    const float4* x    = (const float4*)d_in[0];  // (32,1,2052,768) fp32
    const float*  attn = (const float*)d_in[1];   // (32,2052) fp32
    float4*       out  = (float4*)d_out;          // (32,1,2048,768) fp32

    const int total_threads = H4 * BATCH * NCHUNK;    // 393216
    const int block = 256;
    const int grid  = total_threads / block;          // 1536
    widthap_kernel<<<grid, block, 0, stream>>>(x, attn, out);
}

// Round 3
// 332.594 us; speedup vs baseline: 1.0367x; 1.0367x over previous
//
#include <hip/hip_runtime.h>

// out[b, t, h] = sum_{j=0..4} x[b, t+j, h] * attn[b, t+j]
// B=32, H=768, LENGTH=2048, PADDED=2052, fp32 in/out. Memory-bound streaming.
// TCHUNK=64: read amplification 68/64 = 1.0625. Non-temporal stores (zero
// reuse) and non-temporal x loads (reuse handled in-register; boundary
// overlap absorbed by L3). Native clang vector type for nontemporal builtins.

#define LEN     2048
#define WIDTH   5
#define PADDED  (LEN + WIDTH - 1)   // 2052
#define BATCH   32
#define HDIM    768
#define H4      (HDIM / 4)          // 192 float4 per row
#define TCHUNK  64
#define NCHUNK  (LEN / TCHUNK)      // 32

typedef float vfloat4 __attribute__((ext_vector_type(4)));

__global__ __launch_bounds__(256) void widthap_kernel(
    const vfloat4* __restrict__ x,
    const float*   __restrict__ attn,
    vfloat4*       __restrict__ out)
{
    const int tid   = blockIdx.x * blockDim.x + threadIdx.x;
    const int h4    = tid % H4;            // lane-contiguous -> coalesced
    const int rest  = tid / H4;
    const int b     = rest % BATCH;
    const int chunk = rest / BATCH;
    const int t0 = chunk * TCHUNK;

    const vfloat4* xp = x    + ((size_t)b * PADDED + t0) * H4 + h4;
    const float*   ap = attn +  (size_t)b * PADDED + t0;
    vfloat4*       op = out  + ((size_t)b * LEN    + t0) * H4 + h4;

    // ring of pre-weighted values w[j] = x[t0+j]*attn[t0+j]; each x read once
    vfloat4 w0, w1, w2, w3, w4;

    auto loadw = [&](int j) -> vfloat4 {
        const float   a = ap[j];                                   // cached, wave-broadcast
        const vfloat4 v = __builtin_nontemporal_load(&xp[(size_t)j * H4]); // streaming 16B/lane
        return v * a;
    };

    w0 = loadw(0);
    w1 = loadw(1);
    w2 = loadw(2);
    w3 = loadw(3);

    #pragma unroll 8
    for (int i = 0; i < TCHUNK; ++i) {
        w4 = loadw(i + 4);
        vfloat4 s = w0 + w1 + w2 + w3 + w4;
        __builtin_nontemporal_store(s, &op[(size_t)i * H4]);       // streaming store
        w0 = w1; w1 = w2; w2 = w3; w3 = w4;
    }
}

extern "C" void kernel_launch(void* const* d_in, const int* in_sizes, int n_in,
                              void* d_out, int out_size, void* d_ws, size_t ws_size,
                              hipStream_t stream) {
    const vfloat4* x    = (const vfloat4*)d_in[0];  // (32,1,2052,768) fp32
    const float*   attn = (const float*)d_in[1];    // (32,2052) fp32
    vfloat4*       out  = (vfloat4*)d_out;          // (32,1,2048,768) fp32

    const int total_threads = H4 * BATCH * NCHUNK;    // 196608
    const int block = 256;
    const int grid  = total_threads / block;          // 768 = 3 blocks/CU
    widthap_kernel<<<grid, block, 0, stream>>>(x, attn, out);
}